// Round 1
// baseline (436.684 us; speedup 1.0000x reference)
//
#include <hip/hip_runtime.h>
#include <hip/hip_bf16.h>
#include <math.h>

typedef __bf16 bf16;
typedef __bf16 bf16x4 __attribute__((ext_vector_type(4)));
typedef __bf16 bf16x8 __attribute__((ext_vector_type(8)));
typedef float f32x4 __attribute__((ext_vector_type(4)));

// Problem constants: B=64, ORDER=2, S=256, D=256, H=8, HD=32

// ---------------- kernel 1: W -> bf16, transposed to [ij][n][k] ----------------
__global__ void prep_wt(const float* __restrict__ Wp, bf16* __restrict__ Wt) {
    int gid = blockIdx.x * 256 + threadIdx.x;       // 4*256*256 elements
    int k  = gid & 255;
    int n  = (gid >> 8) & 255;
    int ij = gid >> 16;
    Wt[gid] = (bf16)Wp[(ij * 256 + k) * 256 + n];
}

// ---------------- kernel 2: projection GEMM  xp = x @ W + b  (bf16 MFMA) -------
// grid (128 m-tiles, 4 n-tiles over [j|d], 2 i), 256 threads.
__launch_bounds__(256)
__global__ void proj_gemm(const float* __restrict__ x, const bf16* __restrict__ Wt,
                          const float* __restrict__ bp, bf16* __restrict__ xpb) {
    __shared__ bf16 As[128][40];   // [m][k], padded stride 40
    __shared__ bf16 Bs[128][40];   // [n][k], padded stride 40

    int tid = threadIdx.x;
    int mt = blockIdx.x, nt = blockIdx.y, i = blockIdx.z;
    int n0 = nt * 128;
    int j  = n0 >> 8;          // conv index
    int d0 = n0 & 255;         // column offset within conv
    int m0 = mt * 128;

    // staging mapping: 2 threads per row, 16 k each
    int mr = tid >> 1;
    int kq = (tid & 1) * 16;
    int m  = m0 + mr;
    int b  = m >> 8, s = m & 255;
    const float* xrow = x + (((size_t)(b * 2 + i) * 256 + s) << 8);
    const bf16*  wrow = Wt + (((size_t)(i * 2 + j) * 256 + d0 + mr) << 8);

    int wave = tid >> 6, lane = tid & 63;
    int wm = (wave & 1) * 64, wn = (wave >> 1) * 64;
    int lrow = lane & 15, quad = lane >> 4;

    f32x4 acc[4][4];
#pragma unroll
    for (int a = 0; a < 4; ++a)
#pragma unroll
        for (int c = 0; c < 4; ++c) acc[a][c] = (f32x4){0.f, 0.f, 0.f, 0.f};

    for (int kc = 0; kc < 8; ++kc) {
        int k0 = kc * 32;
        // ---- stage A (fp32 -> bf16) ----
        const float* ap = xrow + k0 + kq;
        f32x4 xa0 = *(const f32x4*)(ap);
        f32x4 xa1 = *(const f32x4*)(ap + 4);
        f32x4 xa2 = *(const f32x4*)(ap + 8);
        f32x4 xa3 = *(const f32x4*)(ap + 12);
        bf16x8 w0, w1;
#pragma unroll
        for (int q = 0; q < 4; ++q) {
            w0[q] = (bf16)xa0[q]; w0[q + 4] = (bf16)xa1[q];
            w1[q] = (bf16)xa2[q]; w1[q + 4] = (bf16)xa3[q];
        }
        *(bf16x8*)&As[mr][kq]     = w0;
        *(bf16x8*)&As[mr][kq + 8] = w1;
        // ---- stage B (already bf16, transposed layout) ----
        const bf16* bpr = wrow + k0 + kq;
        *(bf16x8*)&Bs[mr][kq]     = *(const bf16x8*)bpr;
        *(bf16x8*)&Bs[mr][kq + 8] = *(const bf16x8*)(bpr + 8);
        __syncthreads();
        // ---- MFMA ----
        bf16x8 af[4], bfr[4];
#pragma unroll
        for (int mi = 0; mi < 4; ++mi)
            af[mi] = *(const bf16x8*)&As[wm + mi * 16 + lrow][quad * 8];
#pragma unroll
        for (int ni = 0; ni < 4; ++ni)
            bfr[ni] = *(const bf16x8*)&Bs[wn + ni * 16 + lrow][quad * 8];
#pragma unroll
        for (int mi = 0; mi < 4; ++mi)
#pragma unroll
            for (int ni = 0; ni < 4; ++ni)
                acc[mi][ni] = __builtin_amdgcn_mfma_f32_16x16x32_bf16(af[mi], bfr[ni], acc[mi][ni], 0, 0, 0);
        __syncthreads();
    }

    // ---- epilogue: + bias, write bf16 ----
#pragma unroll
    for (int mi = 0; mi < 4; ++mi) {
#pragma unroll
        for (int r = 0; r < 4; ++r) {
            int rowm = m0 + wm + mi * 16 + quad * 4 + r;
            int bb = rowm >> 8, ss = rowm & 255;
            size_t obase = (((size_t)(i * 2 + j) * 64 + bb) * 256 + ss) << 8;
#pragma unroll
            for (int ni = 0; ni < 4; ++ni) {
                int dcol = d0 + wn + ni * 16 + lrow;
                float v = acc[mi][ni][r] + bp[(i * 2 + j) * 256 + dcol];
                xpb[obase + dcol] = (bf16)v;
            }
        }
    }
}

// ---------------- kernel 3: per-head scores a_s, a_d ---------------------------
// thread = (row, h); row = ((ij)*64+b)*256+s. Output layout [ij][b][h][s].
__global__ void score_k(const bf16* __restrict__ xpb, const float* __restrict__ att_src,
                        const float* __restrict__ att_dst, float* __restrict__ asb,
                        float* __restrict__ adb) {
    int gid = blockIdx.x * 256 + threadIdx.x;   // 4*64*256*8 threads
    int h = gid & 7;
    int r = gid >> 3;
    int s = r & 255;
    int bij = r >> 8;            // ij*64 + b
    int ij = bij >> 6;
    const bf16* row = xpb + ((size_t)r << 8) + h * 32;
    const float* asrc = att_src + (ij * 8 + h) * 32;
    const float* adst = att_dst + (ij * 8 + h) * 32;
    float ssum = 0.f, dsum = 0.f;
#pragma unroll
    for (int c = 0; c < 4; ++c) {
        bf16x8 v = *(const bf16x8*)(row + c * 8);
#pragma unroll
        for (int q = 0; q < 8; ++q) {
            float f = (float)v[q];
            ssum += f * asrc[c * 8 + q];
            dsum += f * adst[c * 8 + q];
        }
    }
    int oidx = (bij * 8 + h) * 256 + s;
    asb[oidx] = ssum;
    adb[oidx] = dsum;
}

// ---------------- kernel 4: fused attention per (b,i,h), both convs ------------
__launch_bounds__(256)
__global__ void attn_k(const int* __restrict__ A, const bf16* __restrict__ xpb,
                       const float* __restrict__ asb, const float* __restrict__ adb,
                       const float* __restrict__ gbias, float* __restrict__ hbuf) {
    int bid = blockIdx.x;               // h + 8*(i + 2*b)
    int h = bid & 7;
    int i = (bid >> 3) & 1;
    int b = bid >> 4;

    __shared__ float as1[256], ad1[256], as2[256], ad2[256];
    __shared__ bf16 E1[256][40];        // [t][s_chunk], padded
    __shared__ bf16 E2[256][40];
    __shared__ bf16 Vt1[32][40];        // [d][s_chunk], padded
    __shared__ bf16 Vt2[32][40];
    __shared__ float l1s[256], l2s[256];

    int tid = threadIdx.x;
    int base1 = (((i * 2 + 0) * 64 + b) * 8 + h) * 256;
    int base2 = (((i * 2 + 1) * 64 + b) * 8 + h) * 256;
    as1[tid] = asb[base1 + tid];
    ad1[tid] = adb[base1 + tid];
    as2[tid] = asb[base2 + tid];
    ad2[tid] = adb[base2 + tid];
    __syncthreads();
    float rd1 = ad1[tid], rd2 = ad2[tid];

    float l1 = 0.f, l2 = 0.f;
    f32x4 acc1[4][2], acc2[4][2];
#pragma unroll
    for (int a = 0; a < 4; ++a)
#pragma unroll
        for (int c = 0; c < 2; ++c) {
            acc1[a][c] = (f32x4){0.f, 0.f, 0.f, 0.f};
            acc2[a][c] = (f32x4){0.f, 0.f, 0.f, 0.f};
        }

    const int* Ab = A + ((size_t)(b * 2 + i) << 16);                 // A[b][i][s][t]
    const bf16* xp1 = xpb + (((size_t)(i * 2 + 0) * 64 + b) << 16);  // + s*256 + d
    const bf16* xp2 = xpb + (((size_t)(i * 2 + 1) * 64 + b) << 16);

    int wave = tid >> 6, lane = tid & 63;
    int lrow = lane & 15, quad = lane >> 4;
    int sV = tid >> 3, dq = (tid & 7) * 4;

    for (int kc = 0; kc < 8; ++kc) {
        int s0 = kc * 32;
        // ---- stage V tiles (transposed: Vt[d][s]) ----
        bf16x4 v1 = *(const bf16x4*)(xp1 + (size_t)(s0 + sV) * 256 + h * 32 + dq);
        bf16x4 v2 = *(const bf16x4*)(xp2 + (size_t)(s0 + sV) * 256 + h * 32 + dq);
#pragma unroll
        for (int q = 0; q < 4; ++q) {
            Vt1[dq + q][sV] = v1[q];
            Vt2[dq + q][sV] = v2[q];
        }
        // ---- build E tiles (thread t = tid owns row t) ----
#pragma unroll 4
        for (int sl = 0; sl < 32; ++sl) {
            int aval = Ab[(s0 + sl) * 256 + tid];
            float u1 = as1[s0 + sl] + rd1;
            float u2 = as2[s0 + sl] + rd2;
            u1 = u1 >= 0.f ? u1 : 0.2f * u1;
            u2 = u2 >= 0.f ? u2 : 0.2f * u2;
            u1 = fminf(u1, 80.f);
            u2 = fminf(u2, 80.f);
            float e1 = (aval == 2 || aval == 4) ? __expf(u1) : 1.0f;
            float e2 = (aval == 3 || aval == 4) ? __expf(u2) : 1.0f;
            l1 += e1; l2 += e2;
            E1[tid][sl] = (bf16)e1;
            E2[tid][sl] = (bf16)e2;
        }
        __syncthreads();
        // ---- MFMA: C[t][d] += E[t][s] * V[s][d]  (wave owns 64 t, all 32 d) ----
        bf16x8 a1[4], a2[4], b1[2], b2[2];
#pragma unroll
        for (int mi = 0; mi < 4; ++mi) {
            a1[mi] = *(const bf16x8*)&E1[wave * 64 + mi * 16 + lrow][quad * 8];
            a2[mi] = *(const bf16x8*)&E2[wave * 64 + mi * 16 + lrow][quad * 8];
        }
#pragma unroll
        for (int ni = 0; ni < 2; ++ni) {
            b1[ni] = *(const bf16x8*)&Vt1[ni * 16 + lrow][quad * 8];
            b2[ni] = *(const bf16x8*)&Vt2[ni * 16 + lrow][quad * 8];
        }
#pragma unroll
        for (int mi = 0; mi < 4; ++mi)
#pragma unroll
            for (int ni = 0; ni < 2; ++ni) {
                acc1[mi][ni] = __builtin_amdgcn_mfma_f32_16x16x32_bf16(a1[mi], b1[ni], acc1[mi][ni], 0, 0, 0);
                acc2[mi][ni] = __builtin_amdgcn_mfma_f32_16x16x32_bf16(a2[mi], b2[ni], acc2[mi][ni], 0, 0, 0);
            }
        __syncthreads();
    }

    l1s[tid] = l1;
    l2s[tid] = l2;
    __syncthreads();

    // ---- epilogue: normalize, + residual (xp) + gbias, write fp32 ----
    float g1b = 0.f, g2b = 0.f; // gbias read per-column below
#pragma unroll
    for (int mi = 0; mi < 4; ++mi) {
#pragma unroll
        for (int r = 0; r < 4; ++r) {
            int t = wave * 64 + mi * 16 + quad * 4 + r;
            float inv1 = 1.0f / l1s[t];
            float inv2 = 1.0f / l2s[t];
            const bf16* x1r = xp1 + (size_t)t * 256 + h * 32;
            const bf16* x2r = xp2 + (size_t)t * 256 + h * 32;
            size_t obase = (((size_t)(b * 2 + i) << 8) + t) << 8;
#pragma unroll
            for (int ni = 0; ni < 2; ++ni) {
                int c = ni * 16 + lrow;
                int dcol = h * 32 + c;
                g1b = gbias[(i * 2 + 0) * 256 + dcol];
                g2b = gbias[(i * 2 + 1) * 256 + dcol];
                float v = acc1[mi][ni][r] * inv1 + acc2[mi][ni][r] * inv2
                        + (float)x1r[c] + (float)x2r[c] + g1b + g2b;
                hbuf[obase + dcol] = v;
            }
        }
    }
}

// ---------------- kernel 5: h + mean(h) then PReLU, in place -------------------
__global__ void final_k(float* __restrict__ out, const float* __restrict__ prelu_a) {
    int gid = blockIdx.x * 256 + threadIdx.x;   // 64*256*64 float4-groups
    int d4 = gid & 63;
    int s  = (gid >> 6) & 255;
    int b  = gid >> 14;
    f32x4* o = (f32x4*)out;
    size_t i0 = (((size_t)(b * 2 + 0) * 256 + s) << 6) + d4;
    size_t i1 = (((size_t)(b * 2 + 1) * 256 + s) << 6) + d4;
    f32x4 h0 = o[i0], h1 = o[i1];
    f32x4 pa = *(const f32x4*)(prelu_a + d4 * 4);
    f32x4 v0, v1;
#pragma unroll
    for (int c = 0; c < 4; ++c) {
        float mn = 0.5f * (h0[c] + h1[c]);
        float a0 = h0[c] + mn;
        float a1 = h1[c] + mn;
        v0[c] = a0 >= 0.f ? a0 : pa[c] * a0;
        v1[c] = a1 >= 0.f ? a1 : pa[c] * a1;
    }
    o[i0] = v0;
    o[i1] = v1;
}

extern "C" void kernel_launch(void* const* d_in, const int* in_sizes, int n_in,
                              void* d_out, int out_size, void* d_ws, size_t ws_size,
                              hipStream_t stream) {
    const float* x       = (const float*)d_in[0];
    const int*   A       = (const int*)d_in[1];
    const float* Wp      = (const float*)d_in[2];
    const float* bp      = (const float*)d_in[3];
    const float* att_src = (const float*)d_in[4];
    const float* att_dst = (const float*)d_in[5];
    const float* gbias   = (const float*)d_in[6];
    const float* prelu_a = (const float*)d_in[7];
    float* out = (float*)d_out;

    char* ws = (char*)d_ws;
    bf16*  Wt  = (bf16*)ws;                                   // 524288 B
    bf16*  xpb = (bf16*)(ws + 524288);                        // 33554432 B
    float* asb = (float*)(ws + 524288 + 33554432);            // 2097152 B
    float* adb = (float*)(ws + 524288 + 33554432 + 2097152);  // 2097152 B

    prep_wt<<<1024, 256, 0, stream>>>(Wp, Wt);
    dim3 gproj(128, 4, 2);
    proj_gemm<<<gproj, 256, 0, stream>>>(x, Wt, bp, xpb);
    score_k<<<2048, 256, 0, stream>>>(xpb, att_src, att_dst, asb, adb);
    attn_k<<<1024, 256, 0, stream>>>(A, xpb, asb, adb, gbias, out);
    final_k<<<4096, 256, 0, stream>>>(out, prelu_a);
}

// Round 2
// 238.478 us; speedup vs baseline: 1.8311x; 1.8311x over previous
//
#include <hip/hip_runtime.h>
#include <hip/hip_bf16.h>
#include <math.h>

typedef __bf16 bf16;
typedef __bf16 bf16x4 __attribute__((ext_vector_type(4)));
typedef __bf16 bf16x8 __attribute__((ext_vector_type(8)));
typedef float f32x4 __attribute__((ext_vector_type(4)));

#define LOG2E 1.44269504f

__device__ inline float fast_exp2(float x) {
#if __has_builtin(__builtin_amdgcn_exp2f)
    return __builtin_amdgcn_exp2f(x);
#else
    return exp2f(x);
#endif
}

// Problem constants: B=64, ORDER=2, S=256, D=256, H=8, HD=32

// ---------------- kernel 1: W -> bf16, transposed to [ij][n][k] ----------------
__global__ void prep_wt(const float* __restrict__ Wp, bf16* __restrict__ Wt) {
    int gid = blockIdx.x * 256 + threadIdx.x;       // 4*256*256 elements
    int k  = gid & 255;
    int n  = (gid >> 8) & 255;
    int ij = gid >> 16;
    Wt[gid] = (bf16)Wp[(ij * 256 + k) * 256 + n];
}

// ---------------- kernel 2: projection GEMM  xp = x @ W + b  (bf16 MFMA) -------
__launch_bounds__(256)
__global__ void proj_gemm(const float* __restrict__ x, const bf16* __restrict__ Wt,
                          const float* __restrict__ bp, bf16* __restrict__ xpb) {
    __shared__ bf16 As[128][40];   // [m][k], padded stride 40
    __shared__ bf16 Bs[128][40];   // [n][k], padded stride 40

    int tid = threadIdx.x;
    int mt = blockIdx.x, nt = blockIdx.y, i = blockIdx.z;
    int n0 = nt * 128;
    int j  = n0 >> 8;          // conv index
    int d0 = n0 & 255;         // column offset within conv
    int m0 = mt * 128;

    int mr = tid >> 1;
    int kq = (tid & 1) * 16;
    int m  = m0 + mr;
    int b  = m >> 8, s = m & 255;
    const float* xrow = x + (((size_t)(b * 2 + i) * 256 + s) << 8);
    const bf16*  wrow = Wt + (((size_t)(i * 2 + j) * 256 + d0 + mr) << 8);

    int wave = tid >> 6, lane = tid & 63;
    int wm = (wave & 1) * 64, wn = (wave >> 1) * 64;
    int lrow = lane & 15, quad = lane >> 4;

    f32x4 acc[4][4];
#pragma unroll
    for (int a = 0; a < 4; ++a)
#pragma unroll
        for (int c = 0; c < 4; ++c) acc[a][c] = (f32x4){0.f, 0.f, 0.f, 0.f};

    for (int kc = 0; kc < 8; ++kc) {
        int k0 = kc * 32;
        const float* ap = xrow + k0 + kq;
        f32x4 xa0 = *(const f32x4*)(ap);
        f32x4 xa1 = *(const f32x4*)(ap + 4);
        f32x4 xa2 = *(const f32x4*)(ap + 8);
        f32x4 xa3 = *(const f32x4*)(ap + 12);
        bf16x8 w0, w1;
#pragma unroll
        for (int q = 0; q < 4; ++q) {
            w0[q] = (bf16)xa0[q]; w0[q + 4] = (bf16)xa1[q];
            w1[q] = (bf16)xa2[q]; w1[q + 4] = (bf16)xa3[q];
        }
        *(bf16x8*)&As[mr][kq]     = w0;
        *(bf16x8*)&As[mr][kq + 8] = w1;
        const bf16* bpr = wrow + k0 + kq;
        *(bf16x8*)&Bs[mr][kq]     = *(const bf16x8*)bpr;
        *(bf16x8*)&Bs[mr][kq + 8] = *(const bf16x8*)(bpr + 8);
        __syncthreads();
        bf16x8 af[4], bfr[4];
#pragma unroll
        for (int mi = 0; mi < 4; ++mi)
            af[mi] = *(const bf16x8*)&As[wm + mi * 16 + lrow][quad * 8];
#pragma unroll
        for (int ni = 0; ni < 4; ++ni)
            bfr[ni] = *(const bf16x8*)&Bs[wn + ni * 16 + lrow][quad * 8];
#pragma unroll
        for (int mi = 0; mi < 4; ++mi)
#pragma unroll
            for (int ni = 0; ni < 4; ++ni)
                acc[mi][ni] = __builtin_amdgcn_mfma_f32_16x16x32_bf16(af[mi], bfr[ni], acc[mi][ni], 0, 0, 0);
        __syncthreads();
    }

#pragma unroll
    for (int mi = 0; mi < 4; ++mi) {
#pragma unroll
        for (int r = 0; r < 4; ++r) {
            int rowm = m0 + wm + mi * 16 + quad * 4 + r;
            int bb = rowm >> 8, ss = rowm & 255;
            size_t obase = (((size_t)(i * 2 + j) * 64 + bb) * 256 + ss) << 8;
#pragma unroll
            for (int ni = 0; ni < 4; ++ni) {
                int dcol = d0 + wn + ni * 16 + lrow;
                float v = acc[mi][ni][r] + bp[(i * 2 + j) * 256 + dcol];
                xpb[obase + dcol] = (bf16)v;
            }
        }
    }
}

// ---------------- kernel 3: per-head scores a_s, a_d (pre-scaled by log2e) -----
__global__ void score_k(const bf16* __restrict__ xpb, const float* __restrict__ att_src,
                        const float* __restrict__ att_dst, float* __restrict__ asb,
                        float* __restrict__ adb) {
    int gid = blockIdx.x * 256 + threadIdx.x;   // 4*64*256*8 threads
    int h = gid & 7;
    int r = gid >> 3;
    int s = r & 255;
    int bij = r >> 8;            // ij*64 + b
    int ij = bij >> 6;
    const bf16* row = xpb + ((size_t)r << 8) + h * 32;
    const float* asrc = att_src + (ij * 8 + h) * 32;
    const float* adst = att_dst + (ij * 8 + h) * 32;
    float ssum = 0.f, dsum = 0.f;
#pragma unroll
    for (int c = 0; c < 4; ++c) {
        bf16x8 v = *(const bf16x8*)(row + c * 8);
#pragma unroll
        for (int q = 0; q < 8; ++q) {
            float f = (float)v[q];
            ssum += f * asrc[c * 8 + q];
            dsum += f * adst[c * 8 + q];
        }
    }
    int oidx = (bij * 8 + h) * 256 + s;
    asb[oidx] = ssum * LOG2E;      // pre-scale: exp(u) == exp2(u*log2e)
    adb[oidx] = dsum * LOG2E;      // lrelu commutes with positive scaling
}

// ---------------- kernel 4: pack adjacency into two bitmask planes -------------
// m1/m2 layout: [b*2+i][kc=8][t=256] u32, bit (s&31) set iff edge for s=kc*32+bit
__global__ void pack_a(const int* __restrict__ A, unsigned* __restrict__ m1,
                       unsigned* __restrict__ m2) {
    int bid = blockIdx.x;          // 256 = ijb*2 + s-half
    int sh = bid & 1;
    int ijb = bid >> 1;            // b*2+i
    int tid = threadIdx.x;
    const int* Ab = A + ((size_t)ijb << 16);
    unsigned w1 = 0, w2 = 0;
#pragma unroll 8
    for (int sl = 0; sl < 128; ++sl) {
        int s = sh * 128 + sl;
        int av = Ab[s * 256 + tid];
        unsigned f1 = (av == 2 || av == 4) ? 1u : 0u;
        unsigned f2 = (av == 3 || av == 4) ? 1u : 0u;
        w1 |= f1 << (s & 31);
        w2 |= f2 << (s & 31);
        if ((s & 31) == 31) {
            int kc = s >> 5;
            m1[(ijb * 8 + kc) * 256 + tid] = w1;
            m2[(ijb * 8 + kc) * 256 + tid] = w2;
            w1 = 0; w2 = 0;
        }
    }
}

// ---------------- kernel 5: fused attention, E built in MFMA A-frag registers --
// grid 1024: (b, i, head-group of 4, t-tile of 64); wave w -> head hg*4+w.
// k-loop is barrier-free: no LDS E/V tiles; V b-frags gathered from global (L2-hot).
__launch_bounds__(256, 3)
__global__ void attn_k(const bf16* __restrict__ xpb, const unsigned* __restrict__ m1,
                       const unsigned* __restrict__ m2, const float* __restrict__ asb,
                       const float* __restrict__ adb, const float* __restrict__ gbias,
                       float* __restrict__ out) {
    int bid = blockIdx.x;
    int tt = bid & 3, hg = (bid >> 2) & 1, i = (bid >> 3) & 1, b = bid >> 4;
    int t0 = tt * 64;
    int tid = threadIdx.x, wave = tid >> 6, lane = tid & 63;
    int lrow = lane & 15, quad = lane >> 4;
    int h = hg * 4 + wave;

    __shared__ float    as_l[2][4][256];   // [conv][wave-head][s]
    __shared__ unsigned ml[2][8][64];      // [conv][kc][t_local]
    __shared__ float    l_lds[2][4][64];   // [conv][wave-head][t_local]

#pragma unroll
    for (int p = 0; p < 8; ++p) {
        int c = p >> 2, w = p & 3;
        as_l[c][w][tid] = asb[(((i * 2 + c) * 64 + b) * 8 + hg * 4 + w) * 256 + tid];
    }
    {
        const unsigned* mp0 = m1 + ((b * 2 + i) * 8) * 256 + t0;
        const unsigned* mp1 = m2 + ((b * 2 + i) * 8) * 256 + t0;
#pragma unroll
        for (int p = 0; p < 4; ++p) {
            int idx = p * 256 + tid;          // 1024 words
            int c = idx >> 9, kc = (idx >> 6) & 7, tl = idx & 63;
            ml[c][kc][tl] = (c == 0 ? mp0 : mp1)[kc * 256 + tl];
        }
    }
    float ad_r[2][4];
#pragma unroll
    for (int c = 0; c < 2; ++c)
#pragma unroll
        for (int mi = 0; mi < 4; ++mi)
            ad_r[c][mi] = adb[(((i * 2 + c) * 64 + b) * 8 + h) * 256 + t0 + mi * 16 + lrow];
    __syncthreads();

    const bf16* xp0 = xpb + ((size_t)((i * 2 + 0) * 64 + b) << 16);
    const bf16* xp1 = xpb + ((size_t)((i * 2 + 1) * 64 + b) << 16);

    f32x4 acc[2][4][2];
#pragma unroll
    for (int c = 0; c < 2; ++c)
#pragma unroll
        for (int mi = 0; mi < 4; ++mi)
#pragma unroll
            for (int ni = 0; ni < 2; ++ni) acc[c][mi][ni] = (f32x4){0.f, 0.f, 0.f, 0.f};
    float lsum[2][4] = {{0.f, 0.f, 0.f, 0.f}, {0.f, 0.f, 0.f, 0.f}};

    for (int kc = 0; kc < 8; ++kc) {
        int s0 = kc * 32;
        // ---- V b-frags: per-lane scalar gather, B[k=quad*8+j][n=lrow] ----
        bf16x8 bfr[2][2];
#pragma unroll
        for (int ni = 0; ni < 2; ++ni) {
            const bf16* vb0 = xp0 + (size_t)(s0 + quad * 8) * 256 + h * 32 + ni * 16 + lrow;
            const bf16* vb1 = xp1 + (size_t)(s0 + quad * 8) * 256 + h * 32 + ni * 16 + lrow;
#pragma unroll
            for (int j = 0; j < 8; ++j) {
                bfr[0][ni][j] = vb0[j * 256];
                bfr[1][ni][j] = vb1[j * 256];
            }
        }
#pragma unroll
        for (int c = 0; c < 2; ++c) {
            float asv[8];
#pragma unroll
            for (int j = 0; j < 8; ++j) asv[j] = as_l[c][wave][s0 + quad * 8 + j];
#pragma unroll
            for (int mi = 0; mi < 4; ++mi) {
                unsigned w = ml[c][kc][mi * 16 + lrow];
                float ad = ad_r[c][mi];
                bf16x8 af;
#pragma unroll
                for (int j = 0; j < 8; ++j) {
                    float u = asv[j] + ad;
                    u = fmaxf(u, 0.2f * u);   // leaky_relu in log2 domain
                    u = fminf(u, 115.f);      // overflow guard (2^115 < bf16 max)
                    float e = fast_exp2(u);
                    e = ((w >> (quad * 8 + j)) & 1u) ? e : 1.0f;  // masked -> exp(0)=1
                    lsum[c][mi] += e;
                    af[j] = (bf16)e;
                }
                acc[c][mi][0] = __builtin_amdgcn_mfma_f32_16x16x32_bf16(af, bfr[c][0], acc[c][mi][0], 0, 0, 0);
                acc[c][mi][1] = __builtin_amdgcn_mfma_f32_16x16x32_bf16(af, bfr[c][1], acc[c][mi][1], 0, 0, 0);
            }
        }
    }

    // ---- complete row sums l_t across quads (s was split quad*8+j) ----
#pragma unroll
    for (int c = 0; c < 2; ++c)
#pragma unroll
        for (int mi = 0; mi < 4; ++mi) {
            float l = lsum[c][mi];
            l += __shfl_xor(l, 16, 64);
            l += __shfl_xor(l, 32, 64);
            if (lane < 16) l_lds[c][wave][mi * 16 + lane] = l;
        }
    __syncthreads();

    // ---- epilogue: normalize, sum convs, + residual + gbias, write fp32 ----
#pragma unroll
    for (int ni = 0; ni < 2; ++ni) {
        int dcol = h * 32 + ni * 16 + lrow;
        float gb = gbias[(i * 2 + 0) * 256 + dcol] + gbias[(i * 2 + 1) * 256 + dcol];
#pragma unroll
        for (int mi = 0; mi < 4; ++mi) {
#pragma unroll
            for (int r = 0; r < 4; ++r) {
                int tl = mi * 16 + quad * 4 + r;
                int t = t0 + tl;
                float inv1 = __builtin_amdgcn_rcpf(l_lds[0][wave][tl]);
                float inv2 = __builtin_amdgcn_rcpf(l_lds[1][wave][tl]);
                float res = (float)xp0[(size_t)t * 256 + dcol] + (float)xp1[(size_t)t * 256 + dcol];
                float v = acc[0][mi][ni][r] * inv1 + acc[1][mi][ni][r] * inv2 + res + gb;
                out[(((size_t)((b * 2 + i) * 256 + t)) << 8) + dcol] = v;
            }
        }
    }
}

// ---------------- kernel 6: h + mean(h) then PReLU, in place -------------------
__global__ void final_k(float* __restrict__ out, const float* __restrict__ prelu_a) {
    int gid = blockIdx.x * 256 + threadIdx.x;   // 64*256*64 float4-groups
    int d4 = gid & 63;
    int s  = (gid >> 6) & 255;
    int b  = gid >> 14;
    f32x4* o = (f32x4*)out;
    size_t i0 = (((size_t)(b * 2 + 0) * 256 + s) << 6) + d4;
    size_t i1 = (((size_t)(b * 2 + 1) * 256 + s) << 6) + d4;
    f32x4 h0 = o[i0], h1 = o[i1];
    f32x4 pa = *(const f32x4*)(prelu_a + d4 * 4);
    f32x4 v0, v1;
#pragma unroll
    for (int c = 0; c < 4; ++c) {
        float mn = 0.5f * (h0[c] + h1[c]);
        float a0 = h0[c] + mn;
        float a1 = h1[c] + mn;
        v0[c] = a0 >= 0.f ? a0 : pa[c] * a0;
        v1[c] = a1 >= 0.f ? a1 : pa[c] * a1;
    }
    o[i0] = v0;
    o[i1] = v1;
}

extern "C" void kernel_launch(void* const* d_in, const int* in_sizes, int n_in,
                              void* d_out, int out_size, void* d_ws, size_t ws_size,
                              hipStream_t stream) {
    const float* x       = (const float*)d_in[0];
    const int*   A       = (const int*)d_in[1];
    const float* Wp      = (const float*)d_in[2];
    const float* bp      = (const float*)d_in[3];
    const float* att_src = (const float*)d_in[4];
    const float* att_dst = (const float*)d_in[5];
    const float* gbias   = (const float*)d_in[6];
    const float* prelu_a = (const float*)d_in[7];
    float* out = (float*)d_out;

    char* ws = (char*)d_ws;
    bf16*     Wt  = (bf16*)ws;                            // 524288 B
    bf16*     xpb = (bf16*)(ws + 524288);                 // 33554432 B
    float*    asb = (float*)(ws + 34078720);              // 2097152 B
    float*    adb = (float*)(ws + 36175872);              // 2097152 B
    unsigned* m1  = (unsigned*)(ws + 38273024);           // 1048576 B
    unsigned* m2  = (unsigned*)(ws + 39321600);           // 1048576 B

    prep_wt<<<1024, 256, 0, stream>>>(Wp, Wt);
    pack_a<<<256, 256, 0, stream>>>(A, m1, m2);
    dim3 gproj(128, 4, 2);
    proj_gemm<<<gproj, 256, 0, stream>>>(x, Wt, bp, xpb);
    score_k<<<2048, 256, 0, stream>>>(xpb, att_src, att_dst, asb, adb);
    attn_k<<<1024, 256, 0, stream>>>(xpb, m1, m2, asb, adb, gbias, out);
    final_k<<<4096, 256, 0, stream>>>(out, prelu_a);
}

// Round 3
// 234.426 us; speedup vs baseline: 1.8628x; 1.0173x over previous
//
#include <hip/hip_runtime.h>
#include <hip/hip_bf16.h>
#include <math.h>

typedef __bf16 bf16;
typedef __bf16 bf16x4 __attribute__((ext_vector_type(4)));
typedef __bf16 bf16x8 __attribute__((ext_vector_type(8)));
typedef float f32x4 __attribute__((ext_vector_type(4)));
typedef unsigned int u32;

#define LOG2E 1.44269504f

__device__ inline float fast_exp2(float x) {
#if __has_builtin(__builtin_amdgcn_exp2f)
    return __builtin_amdgcn_exp2f(x);
#else
    return exp2f(x);
#endif
}

// async global->LDS, 16B per lane; LDS dest must be lane-contiguous (tid*16B)
#define GL2LDS(gp, lp) __builtin_amdgcn_global_load_lds( \
    (const __attribute__((address_space(1))) u32*)(gp),  \
    (__attribute__((address_space(3))) u32*)(lp), 16, 0, 0)

// Problem constants: B=64, ORDER=2, S=256, D=256, H=8, HD=32

// ---------------- kernel 1 (fused prologue): xb = bf16(x); Wt; A bitmasks ------
// blocks [0,4096): x->bf16. [4096,5120): W -> bf16 transposed. [5120,5376): pack A.
__global__ void prep_k(const float* __restrict__ x, const float* __restrict__ Wp,
                       const int* __restrict__ A, bf16* __restrict__ xb,
                       bf16* __restrict__ Wt, unsigned* __restrict__ m1,
                       unsigned* __restrict__ m2) {
    int bid = blockIdx.x;
    int tid = threadIdx.x;
    if (bid < 4096) {
        int gid = bid * 256 + tid;              // 1,048,576 groups of 8
        const f32x4* xp = (const f32x4*)x + (size_t)gid * 2;
        f32x4 a = xp[0], b4 = xp[1];
        bf16x8 o;
#pragma unroll
        for (int c = 0; c < 4; ++c) { o[c] = (bf16)a[c]; o[c + 4] = (bf16)b4[c]; }
        ((bf16x8*)xb)[gid] = o;
    } else if (bid < 5120) {
        int gid = (bid - 4096) * 256 + tid;     // 4*256*256 elements
        int k = gid & 255;
        int n = (gid >> 8) & 255;
        int ij = gid >> 16;
        Wt[gid] = (bf16)Wp[(ij * 256 + k) * 256 + n];
    } else {
        int pb = bid - 5120;                    // 256 = ijb*2 + s-half
        int sh = pb & 1;
        int ijb = pb >> 1;                      // b*2+i
        const int* Ab = A + ((size_t)ijb << 16);
        unsigned w1 = 0, w2 = 0;
#pragma unroll 8
        for (int sl = 0; sl < 128; ++sl) {
            int s = sh * 128 + sl;
            int av = Ab[s * 256 + tid];
            unsigned f1 = (av == 2 || av == 4) ? 1u : 0u;
            unsigned f2 = (av == 3 || av == 4) ? 1u : 0u;
            w1 |= f1 << (s & 31);
            w2 |= f2 << (s & 31);
            if ((s & 31) == 31) {
                int kc = s >> 5;
                m1[(ijb * 8 + kc) * 256 + tid] = w1;
                m2[(ijb * 8 + kc) * 256 + tid] = w2;
                w1 = 0; w2 = 0;
            }
        }
    }
}

// ---------------- kernel 2: projection GEMM (m97-style, global_load_lds) -------
// grid (128 m-tiles, 4 n-tiles over [j|d], 2 i), 256 threads, 128x128 tile.
__launch_bounds__(256)
__global__ void proj_gemm(const bf16* __restrict__ xb, const bf16* __restrict__ Wt,
                          const float* __restrict__ bp, bf16* __restrict__ xpb) {
    __shared__ bf16 As[128 * 32];   // [m][k] contiguous (load_lds requires no pad)
    __shared__ bf16 Bs[128 * 32];   // [n][k]

    int tid = threadIdx.x;
    int mt = blockIdx.x, nt = blockIdx.y, i = blockIdx.z;
    int n0 = nt * 128;
    int j  = n0 >> 8;
    int d0 = n0 & 255;
    int m0 = mt * 128;

    // chunk c -> row c>>2, k-offset (c&3)*8 ; LDS dest = c*16B (lane-contiguous)
    int c0 = tid, c1 = tid + 256;
    int r0 = c0 >> 2, k80 = (c0 & 3) * 8;
    int r1 = c1 >> 2, k81 = (c1 & 3) * 8;
    int gm0 = m0 + r0, gm1 = m0 + r1;
    const bf16* ga0 = xb + (((size_t)((gm0 >> 8) * 2 + i) * 256 + (gm0 & 255)) << 8) + k80;
    const bf16* ga1 = xb + (((size_t)((gm1 >> 8) * 2 + i) * 256 + (gm1 & 255)) << 8) + k81;
    const bf16* gb0 = Wt + (((size_t)(i * 2 + j) * 256 + d0 + r0) << 8) + k80;
    const bf16* gb1 = Wt + (((size_t)(i * 2 + j) * 256 + d0 + r1) << 8) + k81;
    bf16* la0 = As + c0 * 8;
    bf16* la1 = As + c1 * 8;
    bf16* lb0 = Bs + c0 * 8;
    bf16* lb1 = Bs + c1 * 8;

    int wave = tid >> 6, lane = tid & 63;
    int wm = (wave & 1) * 64, wn = (wave >> 1) * 64;
    int lrow = lane & 15, quad = lane >> 4;

    f32x4 acc[4][4];
#pragma unroll
    for (int a = 0; a < 4; ++a)
#pragma unroll
        for (int c = 0; c < 4; ++c) acc[a][c] = (f32x4){0.f, 0.f, 0.f, 0.f};

    for (int kc = 0; kc < 8; ++kc) {
        int k0 = kc * 32;
        GL2LDS(ga0 + k0, la0);
        GL2LDS(ga1 + k0, la1);
        GL2LDS(gb0 + k0, lb0);
        GL2LDS(gb1 + k0, lb1);
        __syncthreads();
        bf16x8 af[4], bfr[4];
#pragma unroll
        for (int mi = 0; mi < 4; ++mi)
            af[mi] = *(const bf16x8*)&As[(wm + mi * 16 + lrow) * 32 + quad * 8];
#pragma unroll
        for (int ni = 0; ni < 4; ++ni)
            bfr[ni] = *(const bf16x8*)&Bs[(wn + ni * 16 + lrow) * 32 + quad * 8];
#pragma unroll
        for (int mi = 0; mi < 4; ++mi)
#pragma unroll
            for (int ni = 0; ni < 4; ++ni)
                acc[mi][ni] = __builtin_amdgcn_mfma_f32_16x16x32_bf16(af[mi], bfr[ni], acc[mi][ni], 0, 0, 0);
        __syncthreads();
    }

#pragma unroll
    for (int mi = 0; mi < 4; ++mi) {
#pragma unroll
        for (int r = 0; r < 4; ++r) {
            int rowm = m0 + wm + mi * 16 + quad * 4 + r;
            int bb = rowm >> 8, ss = rowm & 255;
            size_t obase = (((size_t)(i * 2 + j) * 64 + bb) * 256 + ss) << 8;
#pragma unroll
            for (int ni = 0; ni < 4; ++ni) {
                int dcol = d0 + wn + ni * 16 + lrow;
                float v = acc[mi][ni][r] + bp[(i * 2 + j) * 256 + dcol];
                xpb[obase + dcol] = (bf16)v;
            }
        }
    }
}

// ---------------- kernel 3: scores (pre-scaled log2e) + V transpose ------------
// Vt layout: [ijb=ij*64+b][h][d=32][s=256] bf16
__global__ void score_k(const bf16* __restrict__ xpb, const float* __restrict__ att_src,
                        const float* __restrict__ att_dst, float* __restrict__ asb,
                        float* __restrict__ adb, bf16* __restrict__ Vt) {
    int gid = blockIdx.x * 256 + threadIdx.x;   // 4*64*256*8 threads
    int h = gid & 7;
    int r = gid >> 3;            // (ij*64+b)*256 + s
    int s = r & 255;
    int bij = r >> 8;
    int ij = bij >> 6;
    const bf16* row = xpb + ((size_t)r << 8) + h * 32;
    const float* asrc = att_src + (ij * 8 + h) * 32;
    const float* adst = att_dst + (ij * 8 + h) * 32;
    bf16* vout = Vt + (((size_t)(bij * 8 + h)) << 13) + s;   // *32*256
    float ssum = 0.f, dsum = 0.f;
#pragma unroll
    for (int c = 0; c < 4; ++c) {
        bf16x8 v = *(const bf16x8*)(row + c * 8);
#pragma unroll
        for (int q = 0; q < 8; ++q) {
            float f = (float)v[q];
            ssum += f * asrc[c * 8 + q];
            dsum += f * adst[c * 8 + q];
        }
#pragma unroll
        for (int q = 0; q < 8; ++q) vout[(c * 8 + q) << 8] = v[q];
    }
    int oidx = (bij * 8 + h) * 256 + s;
    asb[oidx] = ssum * LOG2E;
    adb[oidx] = dsum * LOG2E;
}

// ---------------- kernel 4: fused attention, E in A-frag regs, V via Vt --------
// grid 1024: (b, i, head-group of 4, t-tile of 64); wave w -> head hg*4+w.
__launch_bounds__(256, 3)
__global__ void attn_k(const bf16* __restrict__ Vt, const unsigned* __restrict__ m1,
                       const unsigned* __restrict__ m2, const float* __restrict__ asb,
                       const float* __restrict__ adb, const float* __restrict__ gbias,
                       float* __restrict__ out) {
    int bid = blockIdx.x;
    int tt = bid & 3, hg = (bid >> 2) & 1, i = (bid >> 3) & 1, b = bid >> 4;
    int t0 = tt * 64;
    int tid = threadIdx.x, wave = tid >> 6, lane = tid & 63;
    int lrow = lane & 15, quad = lane >> 4;
    int h = hg * 4 + wave;

    __shared__ float    as_l[2][4][256];   // [conv][wave-head][s]
    __shared__ unsigned ml[2][8][64];      // [conv][kc][t_local]
    __shared__ float    l_lds[2][4][64];   // [conv][wave-head][t_local]

#pragma unroll
    for (int p = 0; p < 8; ++p) {
        int c = p >> 2, w = p & 3;
        as_l[c][w][tid] = asb[(((i * 2 + c) * 64 + b) * 8 + hg * 4 + w) * 256 + tid];
    }
    {
        const unsigned* mp0 = m1 + ((b * 2 + i) * 8) * 256 + t0;
        const unsigned* mp1 = m2 + ((b * 2 + i) * 8) * 256 + t0;
#pragma unroll
        for (int p = 0; p < 4; ++p) {
            int idx = p * 256 + tid;          // 1024 words
            int c = idx >> 9, kc = (idx >> 6) & 7, tl = idx & 63;
            ml[c][kc][tl] = (c == 0 ? mp0 : mp1)[kc * 256 + tl];
        }
    }
    float ad_r[2][4];
#pragma unroll
    for (int c = 0; c < 2; ++c)
#pragma unroll
        for (int mi = 0; mi < 4; ++mi)
            ad_r[c][mi] = adb[(((i * 2 + c) * 64 + b) * 8 + h) * 256 + t0 + mi * 16 + lrow];
    __syncthreads();

    const bf16* vt0 = Vt + (((size_t)(((i * 2 + 0) * 64 + b) * 8 + h)) << 13);
    const bf16* vt1 = Vt + (((size_t)(((i * 2 + 1) * 64 + b) * 8 + h)) << 13);

    f32x4 acc[2][4][2];
#pragma unroll
    for (int c = 0; c < 2; ++c)
#pragma unroll
        for (int mi = 0; mi < 4; ++mi)
#pragma unroll
            for (int ni = 0; ni < 2; ++ni) acc[c][mi][ni] = (f32x4){0.f, 0.f, 0.f, 0.f};
    float lsum[2][4] = {{0.f, 0.f, 0.f, 0.f}, {0.f, 0.f, 0.f, 0.f}};

    for (int kc = 0; kc < 8; ++kc) {
        int s0 = kc * 32;
        // ---- V b-frags: one b128 load each (Vt is [d][s]) ----
        bf16x8 bfr[2][2];
#pragma unroll
        for (int ni = 0; ni < 2; ++ni) {
            bfr[0][ni] = *(const bf16x8*)(vt0 + (size_t)(ni * 16 + lrow) * 256 + s0 + quad * 8);
            bfr[1][ni] = *(const bf16x8*)(vt1 + (size_t)(ni * 16 + lrow) * 256 + s0 + quad * 8);
        }
#pragma unroll
        for (int c = 0; c < 2; ++c) {
            float asv[8];
#pragma unroll
            for (int j = 0; j < 8; ++j) asv[j] = as_l[c][wave][s0 + quad * 8 + j];
#pragma unroll
            for (int mi = 0; mi < 4; ++mi) {
                unsigned w = ml[c][kc][mi * 16 + lrow];
                float ad = ad_r[c][mi];
                bf16x8 af;
#pragma unroll
                for (int j = 0; j < 8; ++j) {
                    float u = asv[j] + ad;
                    u = fmaxf(u, 0.2f * u);   // leaky_relu (log2 domain)
                    u = fminf(u, 115.f);      // overflow guard -> v_med3 with above
                    float e = fast_exp2(u);
                    e = ((w >> (quad * 8 + j)) & 1u) ? e : 1.0f;  // masked -> exp(0)=1
                    lsum[c][mi] += e;
                    af[j] = (bf16)e;
                }
                acc[c][mi][0] = __builtin_amdgcn_mfma_f32_16x16x32_bf16(af, bfr[c][0], acc[c][mi][0], 0, 0, 0);
                acc[c][mi][1] = __builtin_amdgcn_mfma_f32_16x16x32_bf16(af, bfr[c][1], acc[c][mi][1], 0, 0, 0);
            }
        }
    }

    // ---- complete row sums across quads ----
#pragma unroll
    for (int c = 0; c < 2; ++c)
#pragma unroll
        for (int mi = 0; mi < 4; ++mi) {
            float l = lsum[c][mi];
            l += __shfl_xor(l, 16, 64);
            l += __shfl_xor(l, 32, 64);
            if (lane < 16) l_lds[c][wave][mi * 16 + lane] = l;
        }
    __syncthreads();

    // ---- epilogue: normalize, sum convs, + residual (from Vt) + gbias ----
#pragma unroll
    for (int ni = 0; ni < 2; ++ni) {
        int dcol = h * 32 + ni * 16 + lrow;
        float gb = gbias[(i * 2 + 0) * 256 + dcol] + gbias[(i * 2 + 1) * 256 + dcol];
        const bf16* r0 = vt0 + (size_t)(ni * 16 + lrow) * 256 + t0;
        const bf16* r1 = vt1 + (size_t)(ni * 16 + lrow) * 256 + t0;
#pragma unroll
        for (int mi = 0; mi < 4; ++mi) {
            bf16x4 rv0 = *(const bf16x4*)(r0 + mi * 16 + quad * 4);
            bf16x4 rv1 = *(const bf16x4*)(r1 + mi * 16 + quad * 4);
#pragma unroll
            for (int r = 0; r < 4; ++r) {
                int tl = mi * 16 + quad * 4 + r;
                int t = t0 + tl;
                float inv1 = __builtin_amdgcn_rcpf(l_lds[0][wave][tl]);
                float inv2 = __builtin_amdgcn_rcpf(l_lds[1][wave][tl]);
                float res = (float)rv0[r] + (float)rv1[r];
                float v = acc[0][mi][ni][r] * inv1 + acc[1][mi][ni][r] * inv2 + res + gb;
                out[(((size_t)((b * 2 + i) * 256 + t)) << 8) + dcol] = v;
            }
        }
    }
}

// ---------------- kernel 5: h + mean(h) then PReLU, in place -------------------
__global__ void final_k(float* __restrict__ out, const float* __restrict__ prelu_a) {
    int gid = blockIdx.x * 256 + threadIdx.x;   // 64*256*64 float4-groups
    int d4 = gid & 63;
    int s  = (gid >> 6) & 255;
    int b  = gid >> 14;
    f32x4* o = (f32x4*)out;
    size_t i0 = (((size_t)(b * 2 + 0) * 256 + s) << 6) + d4;
    size_t i1 = (((size_t)(b * 2 + 1) * 256 + s) << 6) + d4;
    f32x4 h0 = o[i0], h1 = o[i1];
    f32x4 pa = *(const f32x4*)(prelu_a + d4 * 4);
    f32x4 v0, v1;
#pragma unroll
    for (int c = 0; c < 4; ++c) {
        float mn = 0.5f * (h0[c] + h1[c]);
        float a0 = h0[c] + mn;
        float a1 = h1[c] + mn;
        v0[c] = a0 >= 0.f ? a0 : pa[c] * a0;
        v1[c] = a1 >= 0.f ? a1 : pa[c] * a1;
    }
    o[i0] = v0;
    o[i1] = v1;
}

extern "C" void kernel_launch(void* const* d_in, const int* in_sizes, int n_in,
                              void* d_out, int out_size, void* d_ws, size_t ws_size,
                              hipStream_t stream) {
    const float* x       = (const float*)d_in[0];
    const int*   A       = (const int*)d_in[1];
    const float* Wp      = (const float*)d_in[2];
    const float* bp      = (const float*)d_in[3];
    const float* att_src = (const float*)d_in[4];
    const float* att_dst = (const float*)d_in[5];
    const float* gbias   = (const float*)d_in[6];
    const float* prelu_a = (const float*)d_in[7];
    float* out = (float*)d_out;

    char* ws = (char*)d_ws;
    bf16*     Wt  = (bf16*)ws;                            // 524288 B
    bf16*     xpb = (bf16*)(ws + 524288);                 // 33554432 B
    float*    asb = (float*)(ws + 34078720);              // 2097152 B
    float*    adb = (float*)(ws + 36175872);              // 2097152 B
    unsigned* m1  = (unsigned*)(ws + 38273024);           // 1048576 B
    unsigned* m2  = (unsigned*)(ws + 39321600);           // 1048576 B
    bf16*     xbvt = (bf16*)(ws + 40370176);              // 16777216 B (xb, then Vt)

    prep_k<<<5376, 256, 0, stream>>>(x, Wp, A, xbvt, Wt, m1, m2);
    dim3 gproj(128, 4, 2);
    proj_gemm<<<gproj, 256, 0, stream>>>(xbvt, Wt, bp, xpb);
    score_k<<<2048, 256, 0, stream>>>(xpb, att_src, att_dst, asb, adb, xbvt);
    attn_k<<<1024, 256, 0, stream>>>(xbvt, m1, m2, asb, adb, gbias, out);
    final_k<<<4096, 256, 0, stream>>>(out, prelu_a);
}

// Round 5
// 210.391 us; speedup vs baseline: 2.0756x; 1.1142x over previous
//
#include <hip/hip_runtime.h>
#include <hip/hip_bf16.h>
#include <math.h>

typedef __bf16 bf16;
typedef __bf16 bf16x4 __attribute__((ext_vector_type(4)));
typedef __bf16 bf16x8 __attribute__((ext_vector_type(8)));
typedef float f32x4 __attribute__((ext_vector_type(4)));
typedef unsigned int u32;

#define LOG2E 1.44269504f

__device__ inline float fast_exp2(float x) {
#if __has_builtin(__builtin_amdgcn_exp2f)
    return __builtin_amdgcn_exp2f(x);
#else
    return exp2f(x);
#endif
}

// async global->LDS, 16B per lane; LDS dest must be lane-contiguous (tid*16B)
#define GL2LDS(gp, lp) __builtin_amdgcn_global_load_lds( \
    (const __attribute__((address_space(1))) u32*)(gp),  \
    (__attribute__((address_space(3))) u32*)(lp), 16, 0, 0)

// Problem constants: B=64, ORDER=2, S=256, D=256, H=8, HD=32

// ---------------- kernel 1 (fused prologue): xb = bf16(x); Wt; A bitmasks ------
// blocks [0,4096): x->bf16. [4096,5120): W -> bf16 transposed. [5120,5376): pack A.
__global__ void prep_k(const float* __restrict__ x, const float* __restrict__ Wp,
                       const int* __restrict__ A, bf16* __restrict__ xb,
                       bf16* __restrict__ Wt, unsigned* __restrict__ m1,
                       unsigned* __restrict__ m2) {
    int bid = blockIdx.x;
    int tid = threadIdx.x;
    if (bid < 4096) {
        int gid = bid * 256 + tid;              // 1,048,576 groups of 8
        const f32x4* xp = (const f32x4*)x + (size_t)gid * 2;
        f32x4 a = xp[0], b4 = xp[1];
        bf16x8 o;
#pragma unroll
        for (int c = 0; c < 4; ++c) { o[c] = (bf16)a[c]; o[c + 4] = (bf16)b4[c]; }
        ((bf16x8*)xb)[gid] = o;
    } else if (bid < 5120) {
        int gid = (bid - 4096) * 256 + tid;     // 4*256*256 elements
        int k = gid & 255;
        int n = (gid >> 8) & 255;
        int ij = gid >> 16;
        Wt[gid] = (bf16)Wp[(ij * 256 + k) * 256 + n];
    } else {
        int pb = bid - 5120;                    // 256 = ijb*2 + s-half
        int sh = pb & 1;
        int ijb = pb >> 1;                      // b*2+i
        const int* Ab = A + ((size_t)ijb << 16);
        unsigned w1 = 0, w2 = 0;
#pragma unroll 8
        for (int sl = 0; sl < 128; ++sl) {
            int s = sh * 128 + sl;
            int av = Ab[s * 256 + tid];
            unsigned f1 = (av == 2 || av == 4) ? 1u : 0u;
            unsigned f2 = (av == 3 || av == 4) ? 1u : 0u;
            w1 |= f1 << (s & 31);
            w2 |= f2 << (s & 31);
            if ((s & 31) == 31) {
                int kc = s >> 5;
                m1[(ijb * 8 + kc) * 256 + tid] = w1;
                m2[(ijb * 8 + kc) * 256 + tid] = w2;
                w1 = 0; w2 = 0;
            }
        }
    }
}

// ---------------- kernel 2: transposed projection GEMM + scores ----------------
// Computes D[d][s] = (x@W+b)^T directly (swapped MFMA operands), writes Vt
// [ijb][h][d][s] coalesced, and the per-head scores a_s/a_d (x LOG2E).
// grid (128 mt: b,s-half; 4 nt: j,d-half; 2 i), 256 threads, tile 128d x 128s.
__launch_bounds__(256)
__global__ void proj_gemm(const bf16* __restrict__ xb, const bf16* __restrict__ Wt,
                          const float* __restrict__ bp, const float* __restrict__ att_src,
                          const float* __restrict__ att_dst, bf16* __restrict__ Vt,
                          float* __restrict__ asb, float* __restrict__ adb) {
    __shared__ char smem[35840 + 1024];
    bf16* As = (bf16*)smem;            // x tile  [s 128][k 32], contiguous
    bf16* Bs = (bf16*)(smem + 8192);   // Wt tile [d 128][k 32]
    bf16* TL = (bf16*)smem;            // epilogue overlay: [d 128][s stride 140]
    float* attL = (float*)(smem + 35840);   // [which 2][h 4][d 32]

    int tid = threadIdx.x;
    int mt = blockIdx.x, nt = blockIdx.y, i = blockIdx.z;
    int n0 = nt * 128;
    int j = n0 >> 8, d0 = n0 & 255;
    int ij = i * 2 + j;
    int m0 = mt * 128;
    int b = m0 >> 8, shalf = (m0 >> 7) & 1;

    // preload att vectors for this block's 4 heads
    {
        int which = tid >> 7, rest = tid & 127;
        const float* ap = which ? att_dst : att_src;
        attL[tid] = ap[(ij * 8 + (d0 >> 5) + (rest >> 5)) * 32 + (rest & 31)];
    }

    // staging: chunk c -> row c>>2, k-offset (c&3)*8 ; LDS dest = c*16B
    int c0 = tid, c1 = tid + 256;
    int r0 = c0 >> 2, k80 = (c0 & 3) * 8;
    int r1 = c1 >> 2, k81 = (c1 & 3) * 8;
    const bf16* ga0 = xb + (((size_t)((b * 2 + i) * 256 + shalf * 128 + r0)) << 8) + k80;
    const bf16* ga1 = xb + (((size_t)((b * 2 + i) * 256 + shalf * 128 + r1)) << 8) + k81;
    const bf16* gb0 = Wt + (((size_t)(ij * 256 + d0 + r0)) << 8) + k80;
    const bf16* gb1 = Wt + (((size_t)(ij * 256 + d0 + r1)) << 8) + k81;
    bf16* la0 = As + c0 * 8;
    bf16* la1 = As + c1 * 8;
    bf16* lb0 = Bs + c0 * 8;
    bf16* lb1 = Bs + c1 * 8;

    int wave = tid >> 6, lane = tid & 63;
    int wd = (wave & 1) * 64, ws = (wave >> 1) * 64;
    int lrow = lane & 15, quad = lane >> 4;

    f32x4 acc[4][4];   // [dj][sj]
#pragma unroll
    for (int a = 0; a < 4; ++a)
#pragma unroll
        for (int c = 0; c < 4; ++c) acc[a][c] = (f32x4){0.f, 0.f, 0.f, 0.f};

    for (int kc = 0; kc < 8; ++kc) {
        int k0 = kc * 32;
        GL2LDS(ga0 + k0, la0);
        GL2LDS(ga1 + k0, la1);
        GL2LDS(gb0 + k0, lb0);
        GL2LDS(gb1 + k0, lb1);
        __syncthreads();
        bf16x8 wf[4], xf[4];
#pragma unroll
        for (int dj = 0; dj < 4; ++dj)
            wf[dj] = *(const bf16x8*)&Bs[(wd + dj * 16 + lrow) * 32 + quad * 8];
#pragma unroll
        for (int sj = 0; sj < 4; ++sj)
            xf[sj] = *(const bf16x8*)&As[(ws + sj * 16 + lrow) * 32 + quad * 8];
#pragma unroll
        for (int dj = 0; dj < 4; ++dj)
#pragma unroll
            for (int sj = 0; sj < 4; ++sj)
                acc[dj][sj] = __builtin_amdgcn_mfma_f32_16x16x32_bf16(wf[dj], xf[sj], acc[dj][sj], 0, 0, 0);
        __syncthreads();
    }

    // ---- bias + cvt -> TL[d][s] (stride 140: quad offsets spread banks) ----
#pragma unroll
    for (int dj = 0; dj < 4; ++dj) {
#pragma unroll
        for (int r = 0; r < 4; ++r) {
            int dl = wd + dj * 16 + quad * 4 + r;
            float bias = bp[ij * 256 + d0 + dl];
#pragma unroll
            for (int sj = 0; sj < 4; ++sj)
                TL[dl * 140 + ws + sj * 16 + lrow] = (bf16)(acc[dj][sj][r] + bias);
        }
    }
    __syncthreads();

    // ---- Vt store: thread -> (dl = tid>>1, s-half 64) ----
    {
        int dl = tid >> 1, sh64 = (tid & 1) * 64;
        const bf16* src = TL + dl * 140 + sh64;
        bf16* dst = Vt + (((size_t)(ij * 64 + b)) << 16) + (size_t)(d0 + dl) * 256
                    + shalf * 128 + sh64;   // FIX: slab per (ij,b) is 8h*32d*256s = <<16
#pragma unroll
        for (int q = 0; q < 16; ++q)
            *(bf16x4*)(dst + q * 4) = *(const bf16x4*)(src + q * 4);
    }

    // ---- scores: thread -> (s = tid&127, which = tid>>7); 4 heads x dot32 ----
    {
        int s = tid & 127, which = tid >> 7;
        const float* av = attL + which * 128;
        float* outp = which ? adb : asb;
#pragma unroll
        for (int hl = 0; hl < 4; ++hl) {
            float accs = 0.f;
#pragma unroll
            for (int d = 0; d < 32; ++d)
                accs += (float)TL[(hl * 32 + d) * 140 + s] * av[hl * 32 + d];
            int hg = (d0 >> 5) + hl;
            outp[((ij * 64 + b) * 8 + hg) * 256 + shalf * 128 + s] = accs * LOG2E;
        }
    }
}

// ---------------- kernel 3: fused attention, E in A-frag regs, V via Vt --------
// grid 1024: (b, i, head-group of 4, t-tile of 64); wave w -> head hg*4+w.
__launch_bounds__(256, 3)
__global__ void attn_k(const bf16* __restrict__ Vt, const unsigned* __restrict__ m1,
                       const unsigned* __restrict__ m2, const float* __restrict__ asb,
                       const float* __restrict__ adb, const float* __restrict__ gbias,
                       float* __restrict__ out) {
    int bid = blockIdx.x;
    int tt = bid & 3, hg = (bid >> 2) & 1, i = (bid >> 3) & 1, b = bid >> 4;
    int t0 = tt * 64;
    int tid = threadIdx.x, wave = tid >> 6, lane = tid & 63;
    int lrow = lane & 15, quad = lane >> 4;
    int h = hg * 4 + wave;

    __shared__ float    as_l[2][4][256];   // [conv][wave-head][s]
    __shared__ unsigned ml[2][8][64];      // [conv][kc][t_local]
    __shared__ float    l_lds[2][4][64];   // [conv][wave-head][t_local]

#pragma unroll
    for (int p = 0; p < 8; ++p) {
        int c = p >> 2, w = p & 3;
        as_l[c][w][tid] = asb[(((i * 2 + c) * 64 + b) * 8 + hg * 4 + w) * 256 + tid];
    }
    {
        const unsigned* mp0 = m1 + ((b * 2 + i) * 8) * 256 + t0;
        const unsigned* mp1 = m2 + ((b * 2 + i) * 8) * 256 + t0;
#pragma unroll
        for (int p = 0; p < 4; ++p) {
            int idx = p * 256 + tid;          // 1024 words
            int c = idx >> 9, kc = (idx >> 6) & 7, tl = idx & 63;
            ml[c][kc][tl] = (c == 0 ? mp0 : mp1)[kc * 256 + tl];
        }
    }
    float ad_r[2][4];
#pragma unroll
    for (int c = 0; c < 2; ++c)
#pragma unroll
        for (int mi = 0; mi < 4; ++mi)
            ad_r[c][mi] = adb[(((i * 2 + c) * 64 + b) * 8 + h) * 256 + t0 + mi * 16 + lrow];
    __syncthreads();

    const bf16* vt0 = Vt + (((size_t)(((i * 2 + 0) * 64 + b) * 8 + h)) << 13);
    const bf16* vt1 = Vt + (((size_t)(((i * 2 + 1) * 64 + b) * 8 + h)) << 13);

    f32x4 acc[2][4][2];
#pragma unroll
    for (int c = 0; c < 2; ++c)
#pragma unroll
        for (int mi = 0; mi < 4; ++mi)
#pragma unroll
            for (int ni = 0; ni < 2; ++ni) acc[c][mi][ni] = (f32x4){0.f, 0.f, 0.f, 0.f};
    float lsum[2][4] = {{0.f, 0.f, 0.f, 0.f}, {0.f, 0.f, 0.f, 0.f}};

    for (int kc = 0; kc < 8; ++kc) {
        int s0 = kc * 32;
        // ---- V b-frags: one b128 load each (Vt is [d][s]) ----
        bf16x8 bfr[2][2];
#pragma unroll
        for (int ni = 0; ni < 2; ++ni) {
            bfr[0][ni] = *(const bf16x8*)(vt0 + (size_t)(ni * 16 + lrow) * 256 + s0 + quad * 8);
            bfr[1][ni] = *(const bf16x8*)(vt1 + (size_t)(ni * 16 + lrow) * 256 + s0 + quad * 8);
        }
#pragma unroll
        for (int c = 0; c < 2; ++c) {
            float asv[8];
#pragma unroll
            for (int j = 0; j < 8; ++j) asv[j] = as_l[c][wave][s0 + quad * 8 + j];
#pragma unroll
            for (int mi = 0; mi < 4; ++mi) {
                unsigned wb = ml[c][kc][mi * 16 + lrow] >> (quad * 8);
                float ad = ad_r[c][mi];
                bf16x8 af;
#pragma unroll
                for (int j = 0; j < 8; ++j) {
                    float u = asv[j] + ad;
                    u = fmaxf(u, 0.2f * u);           // leaky_relu (log2 domain)
                    u = ((wb >> j) & 1u) ? u : 0.f;   // masked -> exp2(0)=1
                    float e = fast_exp2(u);
                    lsum[c][mi] += e;
                    af[j] = (bf16)e;
                }
                acc[c][mi][0] = __builtin_amdgcn_mfma_f32_16x16x32_bf16(af, bfr[c][0], acc[c][mi][0], 0, 0, 0);
                acc[c][mi][1] = __builtin_amdgcn_mfma_f32_16x16x32_bf16(af, bfr[c][1], acc[c][mi][1], 0, 0, 0);
            }
        }
    }

    // ---- complete row sums across quads ----
#pragma unroll
    for (int c = 0; c < 2; ++c)
#pragma unroll
        for (int mi = 0; mi < 4; ++mi) {
            float l = lsum[c][mi];
            l += __shfl_xor(l, 16, 64);
            l += __shfl_xor(l, 32, 64);
            if (lane < 16) l_lds[c][wave][mi * 16 + lane] = l;
        }
    __syncthreads();

    // ---- epilogue: normalize, sum convs, + residual (from Vt) + gbias ----
#pragma unroll
    for (int ni = 0; ni < 2; ++ni) {
        int dcol = h * 32 + ni * 16 + lrow;
        float gb = gbias[(i * 2 + 0) * 256 + dcol] + gbias[(i * 2 + 1) * 256 + dcol];
        const bf16* r0 = vt0 + (size_t)(ni * 16 + lrow) * 256 + t0;
        const bf16* r1 = vt1 + (size_t)(ni * 16 + lrow) * 256 + t0;
#pragma unroll
        for (int mi = 0; mi < 4; ++mi) {
            bf16x4 rv0 = *(const bf16x4*)(r0 + mi * 16 + quad * 4);
            bf16x4 rv1 = *(const bf16x4*)(r1 + mi * 16 + quad * 4);
#pragma unroll
            for (int r = 0; r < 4; ++r) {
                int tl = mi * 16 + quad * 4 + r;
                int t = t0 + tl;
                float inv1 = __builtin_amdgcn_rcpf(l_lds[0][wave][tl]);
                float inv2 = __builtin_amdgcn_rcpf(l_lds[1][wave][tl]);
                float res = (float)rv0[r] + (float)rv1[r];
                float v = acc[0][mi][ni][r] * inv1 + acc[1][mi][ni][r] * inv2 + res + gb;
                out[(((size_t)((b * 2 + i) * 256 + t)) << 8) + dcol] = v;
            }
        }
    }
}

// ---------------- kernel 4: h + mean(h) then PReLU, in place -------------------
__global__ void final_k(float* __restrict__ out, const float* __restrict__ prelu_a) {
    int gid = blockIdx.x * 256 + threadIdx.x;   // 64*256*64 float4-groups
    int d4 = gid & 63;
    int s  = (gid >> 6) & 255;
    int b  = gid >> 14;
    f32x4* o = (f32x4*)out;
    size_t i0 = (((size_t)(b * 2 + 0) * 256 + s) << 6) + d4;
    size_t i1 = (((size_t)(b * 2 + 1) * 256 + s) << 6) + d4;
    f32x4 h0 = o[i0], h1 = o[i1];
    f32x4 pa = *(const f32x4*)(prelu_a + d4 * 4);
    f32x4 v0, v1;
#pragma unroll
    for (int c = 0; c < 4; ++c) {
        float mn = 0.5f * (h0[c] + h1[c]);
        float a0 = h0[c] + mn;
        float a1 = h1[c] + mn;
        v0[c] = a0 >= 0.f ? a0 : pa[c] * a0;
        v1[c] = a1 >= 0.f ? a1 : pa[c] * a1;
    }
    o[i0] = v0;
    o[i1] = v1;
}

extern "C" void kernel_launch(void* const* d_in, const int* in_sizes, int n_in,
                              void* d_out, int out_size, void* d_ws, size_t ws_size,
                              hipStream_t stream) {
    const float* x       = (const float*)d_in[0];
    const int*   A       = (const int*)d_in[1];
    const float* Wp      = (const float*)d_in[2];
    const float* bp      = (const float*)d_in[3];
    const float* att_src = (const float*)d_in[4];
    const float* att_dst = (const float*)d_in[5];
    const float* gbias   = (const float*)d_in[6];
    const float* prelu_a = (const float*)d_in[7];
    float* out = (float*)d_out;

    char* ws = (char*)d_ws;
    bf16*     Wt  = (bf16*)ws;                            //   524288 B
    unsigned* m1  = (unsigned*)(ws + 524288);             //  1048576 B
    unsigned* m2  = (unsigned*)(ws + 1572864);            //  1048576 B
    float*    asb = (float*)(ws + 2621440);               //  2097152 B
    float*    adb = (float*)(ws + 4718592);               //  2097152 B
    bf16*     xb  = (bf16*)(ws + 6815744);                // 16777216 B
    bf16*     Vt  = (bf16*)(ws + 23592960);               // 16777216 B

    prep_k<<<5376, 256, 0, stream>>>(x, Wp, A, xb, Wt, m1, m2);
    dim3 gproj(128, 4, 2);
    proj_gemm<<<gproj, 256, 0, stream>>>(xb, Wt, bp, att_src, att_dst, Vt, asb, adb);
    attn_k<<<1024, 256, 0, stream>>>(Vt, m1, m2, asb, adb, gbias, out);
    final_k<<<4096, 256, 0, stream>>>(out, prelu_a);
}